// Round 1
// baseline (206.728 us; speedup 1.0000x reference)
//
#include <hip/hip_runtime.h>

// FocusingLoss forward: B=16, WL=8, H=W=512 fp32.
// Pass 1 (reads pred+tgt): per-image {sum t, sum t*y, sum t*x}, global sum (p-t)^2.
// Pass 2 (reads pred):     per-image {sum p, sum p*mask, sum p*dist2} using centroids.
// Final: 128-lane combine -> scalar.

#define HH 512
#define WW 512
#define IMG_PIX (HH * WW)                      // 262144
#define VEC_PER_IMG (IMG_PIX / 4)              // 65536 float4
#define BLOCKS_PER_IMG 16
#define VEC_PER_BLK (VEC_PER_IMG / BLOCKS_PER_IMG)  // 4096
#define THREADS 256
#define EPSF 1e-8f
#define R2 400.0f                              // FOCUS_RADIUS^2

__device__ __forceinline__ float wave_reduce_sum(float v) {
    v += __shfl_down(v, 32);
    v += __shfl_down(v, 16);
    v += __shfl_down(v, 8);
    v += __shfl_down(v, 4);
    v += __shfl_down(v, 2);
    v += __shfl_down(v, 1);
    return v;
}

__global__ void zero_ws_kernel(float* ws, int n) {
    int i = blockIdx.x * blockDim.x + threadIdx.x;
    if (i < n) ws[i] = 0.0f;
}

// acc layout: acc[0] = mse sum; acc[1 + img*3 + {0,1,2}] = {ts, t*y, t*x}
__global__ void __launch_bounds__(THREADS) pass1_kernel(
        const float4* __restrict__ pred, const float4* __restrict__ tgt,
        float* __restrict__ acc) {
    const int img = blockIdx.x / BLOCKS_PER_IMG;
    const int sub = blockIdx.x % BLOCKS_PER_IMG;
    const int base = img * VEC_PER_IMG + sub * VEC_PER_BLK;

    float ts = 0.0f, ty = 0.0f, tx = 0.0f, mse = 0.0f;
    for (int i = threadIdx.x; i < VEC_PER_BLK; i += THREADS) {
        const int vidx = base + i;
        const float4 tv = tgt[vidx];
        const float4 pv = pred[vidx];
        const int pix = (sub * VEC_PER_BLK + i) << 2;   // within-image pixel idx
        const float y  = (float)(pix >> 9);             // /512 (row constant per vec4)
        const float x0 = (float)(pix & 511);
        const float tsum4 = tv.x + tv.y + tv.z + tv.w;
        ts += tsum4;
        ty += y * tsum4;
        tx += x0 * tv.x + (x0 + 1.0f) * tv.y + (x0 + 2.0f) * tv.z + (x0 + 3.0f) * tv.w;
        const float d0 = pv.x - tv.x, d1 = pv.y - tv.y, d2 = pv.z - tv.z, d3 = pv.w - tv.w;
        mse += d0 * d0 + d1 * d1 + d2 * d2 + d3 * d3;
    }
    ts  = wave_reduce_sum(ts);
    ty  = wave_reduce_sum(ty);
    tx  = wave_reduce_sum(tx);
    mse = wave_reduce_sum(mse);
    if ((threadIdx.x & 63) == 0) {
        atomicAdd(&acc[0], mse);
        atomicAdd(&acc[1 + img * 3 + 0], ts);
        atomicAdd(&acc[1 + img * 3 + 1], ty);
        atomicAdd(&acc[1 + img * 3 + 2], tx);
    }
}

// acc2 layout: acc2[img*3 + {0,1,2}] = {pred_total, focus_energy, spread}
__global__ void __launch_bounds__(THREADS) pass2_kernel(
        const float4* __restrict__ pred, const float* __restrict__ acc,
        float* __restrict__ acc2) {
    const int img = blockIdx.x / BLOCKS_PER_IMG;
    const int sub = blockIdx.x % BLOCKS_PER_IMG;
    const float ts = acc[1 + img * 3 + 0];
    const float ts_safe = (ts >= EPSF) ? ts : 1.0f;
    const float cy = acc[1 + img * 3 + 1] / ts_safe;
    const float cx = acc[1 + img * 3 + 2] / ts_safe;
    const int base = img * VEC_PER_IMG + sub * VEC_PER_BLK;

    float ps = 0.0f, fe = 0.0f, sp = 0.0f;
    for (int i = threadIdx.x; i < VEC_PER_BLK; i += THREADS) {
        const int vidx = base + i;
        const float4 pv = pred[vidx];
        const int pix = (sub * VEC_PER_BLK + i) << 2;
        const float y  = (float)(pix >> 9);
        const float x0 = (float)(pix & 511);
        const float dy = y - cy;
        const float dy2 = dy * dy;
        const float dxa = x0 - cx, dxb = x0 + 1.0f - cx, dxc = x0 + 2.0f - cx, dxd = x0 + 3.0f - cx;
        const float q0 = dy2 + dxa * dxa;
        const float q1 = dy2 + dxb * dxb;
        const float q2 = dy2 + dxc * dxc;
        const float q3 = dy2 + dxd * dxd;
        ps += pv.x + pv.y + pv.z + pv.w;
        sp += pv.x * q0 + pv.y * q1 + pv.z * q2 + pv.w * q3;
        fe += (q0 <= R2 ? pv.x : 0.0f) + (q1 <= R2 ? pv.y : 0.0f)
            + (q2 <= R2 ? pv.z : 0.0f) + (q3 <= R2 ? pv.w : 0.0f);
    }
    ps = wave_reduce_sum(ps);
    fe = wave_reduce_sum(fe);
    sp = wave_reduce_sum(sp);
    if ((threadIdx.x & 63) == 0) {
        atomicAdd(&acc2[img * 3 + 0], ps);
        atomicAdd(&acc2[img * 3 + 1], fe);
        atomicAdd(&acc2[img * 3 + 2], sp);
    }
}

__global__ void final_kernel(const float* __restrict__ acc, const float* __restrict__ acc2,
                             float* __restrict__ out, int nimg, float inv_n) {
    __shared__ float red[2];
    const int i = threadIdx.x;
    float v = 0.0f;
    if (i < nimg) {
        const float ts = acc[1 + i * 3 + 0];
        const float pt = acc2[i * 3 + 0];
        if (ts >= EPSF && pt > EPSF) {
            const float r = 1.0f - acc2[i * 3 + 1] / pt;   // 1 - focus_energy/pt
            v = 10.0f * r * r + acc2[i * 3 + 2] / pt;      // FOCUS_WEIGHT*fl + spread/pt
        }
    }
    v = wave_reduce_sum(v);
    if ((i & 63) == 0) red[i >> 6] = v;
    __syncthreads();
    if (i == 0) out[0] = acc[0] * inv_n + red[0] + red[1];
}

extern "C" void kernel_launch(void* const* d_in, const int* in_sizes, int n_in,
                              void* d_out, int out_size, void* d_ws, size_t ws_size,
                              hipStream_t stream) {
    const float* pred = (const float*)d_in[0];
    const float* tgt  = (const float*)d_in[1];
    float* out = (float*)d_out;
    float* ws  = (float*)d_ws;

    const int n = in_sizes[0];                 // 33554432
    const int nimg = n / IMG_PIX;              // 128

    float* acc  = ws;                          // 1 + nimg*3 floats
    float* acc2 = ws + 1 + nimg * 3;           // nimg*3 floats
    const int ws_floats = 1 + nimg * 6;

    zero_ws_kernel<<<(ws_floats + 255) / 256, 256, 0, stream>>>(ws, ws_floats);

    const int grid = nimg * BLOCKS_PER_IMG;    // 2048 blocks
    pass1_kernel<<<grid, THREADS, 0, stream>>>((const float4*)pred, (const float4*)tgt, acc);
    pass2_kernel<<<grid, THREADS, 0, stream>>>((const float4*)pred, acc, acc2);
    final_kernel<<<1, 128, 0, stream>>>(acc, acc2, out, nimg, 1.0f / (float)n);
}

// Round 2
// 63.858 us; speedup vs baseline: 3.2373x; 3.2373x over previous
//
#include <hip/hip_runtime.h>

// FocusingLoss forward, fused. B*WL=128 images of 512x512 fp32.
// Kernel A (one full pass over pred+tgt, 268 MB):
//   per image: ts=sum t, ty=sum t*y, tx=sum t*x, mse=sum (p-t)^2,
//              m0=sum p, my=sum p*y, mx=sum p*x, m2=sum p*(x^2+y^2)
//   spread is recovered as m2 - 2cy*my - 2cx*mx + (cy^2+cx^2)*m0 (no 2nd pass).
// Kernel B (tiny): focus_energy = sum p over disc dist^2<=400 around centroid
//   (<=43x43 window, ~7 KB/image).
// Kernel C: 128-thread finalize in double.

#define HH 512
#define WW 512
#define IMG_PIX (HH * WW)                           // 262144
#define VEC_PER_IMG (IMG_PIX / 4)                   // 65536 float4
#define BLOCKS_PER_IMG 16
#define VEC_PER_BLK (VEC_PER_IMG / BLOCKS_PER_IMG)  // 4096
#define THREADS 256
#define ITERS (VEC_PER_BLK / THREADS)               // 16
#define EPSF 1e-8f
#define R2 400.0f

__device__ __forceinline__ float wave_reduce_sum(float v) {
    v += __shfl_down(v, 32);
    v += __shfl_down(v, 16);
    v += __shfl_down(v, 8);
    v += __shfl_down(v, 4);
    v += __shfl_down(v, 2);
    v += __shfl_down(v, 1);
    return v;
}

__device__ __forceinline__ double wave_reduce_sum_d(double v) {
    v += __shfl_down(v, 32);
    v += __shfl_down(v, 16);
    v += __shfl_down(v, 8);
    v += __shfl_down(v, 4);
    v += __shfl_down(v, 2);
    v += __shfl_down(v, 1);
    return v;
}

// acc layout per image (8 floats): 0:ts 1:ty 2:tx 3:mse 4:m0 5:my 6:mx 7:m2
__global__ void __launch_bounds__(THREADS) stream_kernel(
        const float4* __restrict__ pred, const float4* __restrict__ tgt,
        float* __restrict__ acc) {
    const int img = blockIdx.x / BLOCKS_PER_IMG;
    const int sub = blockIdx.x % BLOCKS_PER_IMG;
    const int base = img * VEC_PER_IMG + sub * VEC_PER_BLK;

    float ts = 0.f, ty = 0.f, tx = 0.f, mse = 0.f;
    float m0 = 0.f, my = 0.f, mx = 0.f, m2 = 0.f;

#pragma unroll 4
    for (int j = 0; j < ITERS; ++j) {
        const int i = j * THREADS + threadIdx.x;
        const int vidx = base + i;
        const float4 tv = tgt[vidx];
        const float4 pv = pred[vidx];
        const int pix = (sub * VEC_PER_BLK + i) << 2;   // within-image pixel idx
        const float y  = (float)(pix >> 9);
        const float x0 = (float)(pix & 511);
        const float x1 = x0 + 1.f, x2 = x0 + 2.f, x3 = x0 + 3.f;

        const float tsum = tv.x + tv.y + tv.z + tv.w;
        ts += tsum;
        ty += y * tsum;
        tx += x0 * tv.x + x1 * tv.y + x2 * tv.z + x3 * tv.w;

        const float d0 = pv.x - tv.x, d1 = pv.y - tv.y,
                    d2 = pv.z - tv.z, d3 = pv.w - tv.w;
        mse += d0 * d0 + d1 * d1 + d2 * d2 + d3 * d3;

        const float psum = pv.x + pv.y + pv.z + pv.w;
        m0 += psum;
        my += y * psum;
        mx += x0 * pv.x + x1 * pv.y + x2 * pv.z + x3 * pv.w;
        const float y2 = y * y;
        m2 += pv.x * (y2 + x0 * x0) + pv.y * (y2 + x1 * x1)
            + pv.z * (y2 + x2 * x2) + pv.w * (y2 + x3 * x3);
    }

    float vals[8] = {ts, ty, tx, mse, m0, my, mx, m2};
    __shared__ float red[4][8];
    const int wid = threadIdx.x >> 6, lane = threadIdx.x & 63;
#pragma unroll
    for (int k = 0; k < 8; ++k) vals[k] = wave_reduce_sum(vals[k]);
    if (lane == 0)
#pragma unroll
        for (int k = 0; k < 8; ++k) red[wid][k] = vals[k];
    __syncthreads();
    if (threadIdx.x < 8) {
        const int k = threadIdx.x;
        const float s = red[0][k] + red[1][k] + red[2][k] + red[3][k];
        atomicAdd(&acc[img * 8 + k], s);   // 16 blocks contend per address
    }
}

// one wave per image; focus_energy over the <=43x43 window around centroid
__global__ void __launch_bounds__(64) focus_kernel(
        const float* __restrict__ pred, const float* __restrict__ acc,
        float* __restrict__ fe_out) {
    const int img = blockIdx.x;
    const float ts = acc[img * 8 + 0];
    float fe = 0.f;
    if (ts >= EPSF) {
        const float cy = acc[img * 8 + 1] / ts;
        const float cx = acc[img * 8 + 2] / ts;
        const int ylo = max(0, (int)ceilf(cy - 20.f) - 1);
        const int yhi = min(HH - 1, (int)floorf(cy + 20.f) + 1);
        const int xlo = max(0, (int)ceilf(cx - 20.f) - 1);
        const int xhi = min(WW - 1, (int)floorf(cx + 20.f) + 1);
        const float* p = pred + (size_t)img * IMG_PIX;
        const int xx = xlo + (int)threadIdx.x;
        if (xx <= xhi) {
            const float dx = (float)xx - cx;
            const float dx2 = dx * dx;
            for (int y = ylo; y <= yhi; ++y) {
                const float dy = (float)y - cy;
                if (dy * dy + dx2 <= R2) fe += p[(y << 9) + xx];
            }
        }
    }
    fe = wave_reduce_sum(fe);
    if (threadIdx.x == 0) fe_out[img] = fe;
}

__global__ void __launch_bounds__(128) final_kernel(
        const float* __restrict__ acc, const float* __restrict__ fe,
        float* __restrict__ out, int nimg, float inv_n) {
    const int i = threadIdx.x;
    double v = 0.0, m = 0.0;
    if (i < nimg) {
        const float* a = acc + i * 8;
        m = (double)a[3];
        const float ts = a[0];
        const float pt = a[4];
        if (ts >= EPSF && pt > EPSF) {
            const double cy = (double)a[1] / (double)ts;
            const double cx = (double)a[2] / (double)ts;
            const double spread = (double)a[7] - 2.0 * cy * (double)a[5]
                                - 2.0 * cx * (double)a[6]
                                + (cy * cy + cx * cx) * (double)a[4];
            const double r = 1.0 - (double)fe[i] / (double)pt;
            v = 10.0 * r * r + spread / (double)pt;
        }
    }
    __shared__ double redv[2], redm[2];
    v = wave_reduce_sum_d(v);
    m = wave_reduce_sum_d(m);
    if ((i & 63) == 0) { redv[i >> 6] = v; redm[i >> 6] = m; }
    __syncthreads();
    if (i == 0)
        out[0] = (float)((redm[0] + redm[1]) * (double)inv_n + redv[0] + redv[1]);
}

extern "C" void kernel_launch(void* const* d_in, const int* in_sizes, int n_in,
                              void* d_out, int out_size, void* d_ws, size_t ws_size,
                              hipStream_t stream) {
    const float* pred = (const float*)d_in[0];
    const float* tgt  = (const float*)d_in[1];
    float* out = (float*)d_out;
    float* ws  = (float*)d_ws;

    const int n = in_sizes[0];                 // 33554432
    const int nimg = n / IMG_PIX;              // 128

    float* acc = ws;                           // nimg*8
    float* fe  = ws + nimg * 8;                // nimg

    hipMemsetAsync(ws, 0, (size_t)nimg * 9 * sizeof(float), stream);

    const int grid = nimg * BLOCKS_PER_IMG;    // 2048 blocks
    stream_kernel<<<grid, THREADS, 0, stream>>>(
        (const float4*)pred, (const float4*)tgt, acc);
    focus_kernel<<<nimg, 64, 0, stream>>>(pred, acc, fe);
    final_kernel<<<1, 128, 0, stream>>>(acc, fe, out, nimg, 1.0f / (float)n);
}